// Round 2
// baseline (401.084 us; speedup 1.0000x reference)
//
#include <hip/hip_runtime.h>
#include <hip/hip_bf16.h>

#define B_ 128
#define S_ 200
#define QN_ 20000
#define V_ 128
#define K_ 128
#define C_ 64
#define SUM_ 128

// ---- dtype-generic loads (BF=true: bf16, BF=false: fp32) ----
template<bool BF>
__device__ __forceinline__ float ld(const void* p, int i) {
    if (BF) return __bfloat162float(((const __hip_bfloat16*)p)[i]);
    return ((const float*)p)[i];
}
template<bool BF>
__device__ __forceinline__ float2 ld2(const void* p, int i) {  // elements 2i, 2i+1
    if (BF) {
        __hip_bfloat162 v = ((const __hip_bfloat162*)p)[i];
        return make_float2(__bfloat162float(v.x), __bfloat162float(v.y));
    }
    return ((const float2*)p)[i];
}

// ---- probe: decide bf16 vs fp32 from erase_b byte patterns ----
// erase_b: 128 elements, |x| <= 1/sqrt(128) ~ 0.088.
// bf16 data: low 16 bits of each u32 word = a small bf16 value.
// fp32 data: low 16 bits = random mantissa bits -> wild bf16 values.
__global__ void dtype_probe(const void* __restrict__ erase_b, int* __restrict__ flag) {
    if (threadIdx.x == 0 && blockIdx.x == 0) {
        const unsigned* w = (const unsigned*)erase_b;
        int bad = 0;
        for (int i = 0; i < 64; ++i) {
            unsigned lo = w[i] & 0xffffu;
            float f = __uint_as_float(lo << 16);
            if (!(fabsf(f) <= 0.5f)) bad++;  // NaN also fails the <= test
        }
        *flag = (bad <= 8) ? 1 : 0;  // 1 = bf16
    }
}

// ================= Phase 1 =================
template<bool BF>
__device__ __forceinline__ void phase1_body(
    const void* q_emb, const void* i_emb, const void* key_memory,
    const void* erase_W, const void* erase_b, const void* add_W, const void* add_b,
    const int* __restrict__ input,
    float* __restrict__ e_buf, float* __restrict__ a_buf, float* __restrict__ w_buf,
    float* iv, float* qv)
{
    const int p = blockIdx.x;   // 0 .. B*S-1
    const int t = threadIdx.x;  // 0 .. 127
    const int idx = input[p];
    const int qid = (idx > QN_) ? (idx - QN_) : idx;
    iv[t] = ld<BF>(i_emb, idx * V_ + t);
    qv[t] = ld<BF>(q_emb, qid * K_ + t);
    __syncthreads();

    // threads 0..63 -> erase (2 output columns each), 64..127 -> add
    const int half = t >> 6;
    const int tt = t & 63;
    const void* W = half ? add_W : erase_W;
    const void* bias = half ? add_b : erase_b;
    const float2 bb = ld2<BF>(bias, tt);
    float acc0 = bb.x, acc1 = bb.y;
    #pragma unroll 8
    for (int i = 0; i < V_; ++i) {
        const float x = iv[i];
        const float2 wv = ld2<BF>(W, i * 64 + tt);  // W[i][2tt], W[i][2tt+1]
        acc0 += x * wv.x;
        acc1 += x * wv.y;
    }
    if (half == 0) {
        const float o0 = 1.f / (1.f + expf(-acc0));
        const float o1 = 1.f / (1.f + expf(-acc1));
        ((float2*)(e_buf + (size_t)p * V_))[tt] = make_float2(o0, o1);
    } else {
        ((float2*)(a_buf + (size_t)p * V_))[tt] = make_float2(tanhf(acc0), tanhf(acc1));
    }

    // w = softmax(qv @ key_memory) over C=64 (wave 0)
    if (t < C_) {
        float acc = 0.f;
        #pragma unroll 8
        for (int i = 0; i < K_; ++i)
            acc += qv[i] * ld<BF>(key_memory, i * C_ + t);
        float m = acc;
        for (int off = 32; off > 0; off >>= 1)
            m = fmaxf(m, __shfl_xor(m, off, 64));
        const float ex = expf(acc - m);
        float ssum = ex;
        for (int off = 32; off > 0; off >>= 1)
            ssum += __shfl_xor(ssum, off, 64);
        w_buf[(size_t)p * C_ + t] = ex / ssum;
    }
}

__global__ __launch_bounds__(128) void dkvmn_phase1(
    const void* q_emb, const void* i_emb, const void* key_memory,
    const void* erase_W, const void* erase_b, const void* add_W, const void* add_b,
    const int* __restrict__ input,
    float* e_buf, float* a_buf, float* w_buf, const int* __restrict__ flag)
{
    __shared__ float iv[V_];
    __shared__ float qv[K_];
    if (*flag)
        phase1_body<true>(q_emb, i_emb, key_memory, erase_W, erase_b, add_W, add_b,
                          input, e_buf, a_buf, w_buf, iv, qv);
    else
        phase1_body<false>(q_emb, i_emb, key_memory, erase_W, erase_b, add_W, add_b,
                           input, e_buf, a_buf, w_buf, iv, qv);
}

// ================= Phase 2 =================
struct P2Shared {
    float lse[V_], lsa[V_], lsw[C_];
    float lsmem[V_ * 65];   // +1 pad: conflict-free row reads in readout
    float qvl[K_], wtl[C_], readl[V_], summl[SUM_];
};

template<bool BF>
__device__ __forceinline__ void phase2_body(
    const void* q_emb, const void* key_memory, const void* init_value_memory,
    const void* summ_W, const void* summ_b, const void* out_W, const void* out_b,
    const int* __restrict__ target_id,
    const float* __restrict__ e_buf, const float* __restrict__ a_buf,
    const float* __restrict__ w_buf,
    void* outp, P2Shared& sm)
{
    const int b = blockIdx.x;
    const int t = threadIdx.x;  // 0..511

    // memory state: flat = t + 512k  ->  v = (t>>6)+8k, c = t&63
    float mem[16];
    #pragma unroll
    for (int k = 0; k < 16; ++k)
        mem[k] = ld<BF>(init_value_memory, t + 512 * k);

    const float* eb = e_buf + (size_t)b * S_ * V_;
    const float* ab = a_buf + (size_t)b * S_ * V_;
    const float* wb = w_buf + (size_t)b * S_ * C_;

    // one-step register prefetch to hide L2 latency
    float nxt = 0.f;
    if (t < 128)       nxt = eb[t];
    else if (t < 256)  nxt = ab[t - 128];
    else if (t < 320)  nxt = wb[t - 256];

    const int wvid = t >> 6;  // 0..7
    for (int s = 0; s < S_; ++s) {
        if (t < 128)       sm.lse[t] = nxt;
        else if (t < 256)  sm.lsa[t - 128] = nxt;
        else if (t < 320)  sm.lsw[t - 256] = nxt;
        __syncthreads();
        if (s + 1 < S_) {
            if (t < 128)       nxt = eb[(s + 1) * V_ + t];
            else if (t < 256)  nxt = ab[(s + 1) * V_ + (t - 128)];
            else if (t < 320)  nxt = wb[(s + 1) * C_ + (t - 256)];
        }
        const float wv = sm.lsw[t & 63];
        #pragma unroll
        for (int k = 0; k < 16; ++k) {
            const int v = wvid + 8 * k;
            mem[k] = mem[k] * (1.f - sm.lse[v] * wv) + sm.lsa[v] * wv;
        }
        __syncthreads();
    }

    // spill memory state to LDS (padded stride 65)
    #pragma unroll
    for (int k = 0; k < 16; ++k) {
        const int v = wvid + 8 * k;
        sm.lsmem[v * 65 + (t & 63)] = mem[k];
    }
    if (t < 128) sm.qvl[t] = ld<BF>(q_emb, target_id[b] * K_ + t);
    __syncthreads();

    // wt = softmax(qv @ key_memory)  (wave 0)
    if (t < 64) {
        float acc = 0.f;
        #pragma unroll 8
        for (int i = 0; i < K_; ++i)
            acc += sm.qvl[i] * ld<BF>(key_memory, i * C_ + t);
        float m = acc;
        for (int off = 32; off > 0; off >>= 1)
            m = fmaxf(m, __shfl_xor(m, off, 64));
        const float ex = expf(acc - m);
        float ssum = ex;
        for (int off = 32; off > 0; off >>= 1)
            ssum += __shfl_xor(ssum, off, 64);
        sm.wtl[t] = ex / ssum;
    }
    __syncthreads();

    // read[v] = sum_c mem[v,c] * wt[c]
    if (t < 128) {
        float acc = 0.f;
        #pragma unroll 8
        for (int c = 0; c < C_; ++c)
            acc += sm.lsmem[t * 65 + c] * sm.wtl[c];
        sm.readl[t] = acc;
    }
    __syncthreads();

    // summ = tanh([read, qv] @ summ_W + summ_b)
    if (t < 128) {
        float acc = ld<BF>(summ_b, t);
        #pragma unroll 8
        for (int i = 0; i < 128; ++i)
            acc += sm.readl[i] * ld<BF>(summ_W, i * SUM_ + t);
        #pragma unroll 8
        for (int i = 0; i < 128; ++i)
            acc += sm.qvl[i] * ld<BF>(summ_W, (128 + i) * SUM_ + t);
        sm.summl[t] = tanhf(acc);
    }
    __syncthreads();

    // out = summ @ out_W + out_b  (scalar per batch)
    if (t < 64) {
        float pacc = sm.summl[t] * ld<BF>(out_W, t) + sm.summl[t + 64] * ld<BF>(out_W, t + 64);
        for (int off = 32; off > 0; off >>= 1)
            pacc += __shfl_xor(pacc, off, 64);
        if (t == 0) {
            const float res = pacc + ld<BF>(out_b, 0);
            if (BF) ((__hip_bfloat16*)outp)[b] = __float2bfloat16(res);
            else    ((float*)outp)[b] = res;
        }
    }
}

__global__ __launch_bounds__(512) void dkvmn_phase2(
    const void* q_emb, const void* key_memory, const void* init_value_memory,
    const void* summ_W, const void* summ_b, const void* out_W, const void* out_b,
    const int* __restrict__ target_id,
    const float* e_buf, const float* a_buf, const float* w_buf,
    void* outp, const int* __restrict__ flag)
{
    __shared__ P2Shared sm;
    if (*flag)
        phase2_body<true>(q_emb, key_memory, init_value_memory, summ_W, summ_b,
                          out_W, out_b, target_id, e_buf, a_buf, w_buf, outp, sm);
    else
        phase2_body<false>(q_emb, key_memory, init_value_memory, summ_W, summ_b,
                           out_W, out_b, target_id, e_buf, a_buf, w_buf, outp, sm);
}

extern "C" void kernel_launch(void* const* d_in, const int* in_sizes, int n_in,
                              void* d_out, int out_size, void* d_ws, size_t ws_size,
                              hipStream_t stream) {
    const void* q_emb             = d_in[0];
    const void* i_emb             = d_in[1];
    const void* key_memory        = d_in[2];
    const void* init_value_memory = d_in[3];
    const void* erase_W           = d_in[4];
    const void* erase_b           = d_in[5];
    const void* add_W             = d_in[6];
    const void* add_b             = d_in[7];
    const void* summ_W            = d_in[8];
    const void* summ_b            = d_in[9];
    const void* out_W             = d_in[10];
    const void* out_b             = d_in[11];
    const int* input     = (const int*)d_in[12];
    const int* target_id = (const int*)d_in[13];

    // workspace: [flag (64B)] [e B*S*V f32] [a B*S*V f32] [w B*S*C f32]
    int* flag    = (int*)d_ws;
    float* e_buf = (float*)((char*)d_ws + 64);
    float* a_buf = e_buf + (size_t)B_ * S_ * V_;
    float* w_buf = a_buf + (size_t)B_ * S_ * V_;

    dtype_probe<<<1, 64, 0, stream>>>(erase_b, flag);
    dkvmn_phase1<<<B_ * S_, 128, 0, stream>>>(
        q_emb, i_emb, key_memory, erase_W, erase_b, add_W, add_b,
        input, e_buf, a_buf, w_buf, flag);
    dkvmn_phase2<<<B_, 512, 0, stream>>>(
        q_emb, key_memory, init_value_memory, summ_W, summ_b, out_W, out_b,
        target_id, e_buf, a_buf, w_buf, (void*)d_out, flag);
}

// Round 3
// 221.841 us; speedup vs baseline: 1.8080x; 1.8080x over previous
//
#include <hip/hip_runtime.h>
#include <hip/hip_bf16.h>

#define B_ 128
#define S_ 200
#define QN_ 20000
#define V_ 128
#define K_ 128
#define C_ 64
#define SUM_ 128
#define P1P 16   // positions per phase1 block

// ---- dtype-generic loads (BF=true: bf16, BF=false: fp32) ----
template<bool BF>
__device__ __forceinline__ float ld(const void* p, long long i) {
    if (BF) return __bfloat162float(((const __hip_bfloat16*)p)[i]);
    return ((const float*)p)[i];
}
template<bool BF>
__device__ __forceinline__ float2 ld2(const void* p, long long i) {  // elems 2i, 2i+1
    if (BF) {
        __hip_bfloat162 v = ((const __hip_bfloat162*)p)[i];
        return make_float2(__bfloat162float(v.x), __bfloat162float(v.y));
    }
    return ((const float2*)p)[i];
}
// 16 consecutive elements starting at elem offset off (off must be mult. of 16)
template<bool BF>
__device__ __forceinline__ void ld16(const void* p, long long off, float* out) {
    if (BF) {
        const uint4* q = (const uint4*)((const unsigned short*)p + off);
        uint4 u0 = q[0], u1 = q[1];
        unsigned uu[8] = {u0.x, u0.y, u0.z, u0.w, u1.x, u1.y, u1.z, u1.w};
        #pragma unroll
        for (int k = 0; k < 8; ++k) {
            out[2 * k]     = __uint_as_float(uu[k] << 16);
            out[2 * k + 1] = __uint_as_float(uu[k] & 0xffff0000u);
        }
    } else {
        const float4* q = (const float4*)((const float*)p + off);
        float4 f0 = q[0], f1 = q[1], f2 = q[2], f3 = q[3];
        out[0]=f0.x; out[1]=f0.y; out[2]=f0.z; out[3]=f0.w;
        out[4]=f1.x; out[5]=f1.y; out[6]=f1.z; out[7]=f1.w;
        out[8]=f2.x; out[9]=f2.y; out[10]=f2.z; out[11]=f2.w;
        out[12]=f3.x; out[13]=f3.y; out[14]=f3.z; out[15]=f3.w;
    }
}

// ---- probe: decide bf16 vs fp32 from erase_b byte patterns ----
__global__ void dtype_probe(const void* __restrict__ erase_b, int* __restrict__ flag) {
    if (threadIdx.x == 0 && blockIdx.x == 0) {
        const unsigned* w = (const unsigned*)erase_b;
        int bad = 0;
        for (int i = 0; i < 64; ++i) {
            unsigned lo = w[i] & 0xffffu;
            float f = __uint_as_float(lo << 16);
            if (!(fabsf(f) <= 0.5f)) bad++;
        }
        *flag = (bad <= 8) ? 1 : 0;  // 1 = bf16
    }
}

// ================= Phase 1: batched mat-vecs, P=16 positions/block =================
template<bool BF>
__device__ __forceinline__ void phase1_body(
    const void* q_emb, const void* i_emb, const void* key_memory,
    const void* erase_W, const void* erase_b, const void* add_W, const void* add_b,
    const int* __restrict__ input,
    float* __restrict__ e_buf, float* __restrict__ a_buf, float* __restrict__ w_buf,
    float* ivT, float* qvT, int* sidx, int* sqid)
{
    const int p0 = blockIdx.x * P1P;
    const int t = threadIdx.x;  // 0..191

    if (t < P1P) {
        const int ix = input[p0 + t];
        sidx[t] = ix;
        sqid[t] = ix > QN_ ? ix - QN_ : ix;
    }
    __syncthreads();

    // stage 256 jobs: (tensor, p, 16-elem segment) -> transposed LDS
    for (int rep = 0; rep < 2; ++rep) {
        const int j = (rep == 0) ? t : t + 192;
        if (j < 256) {
            const int tensor = j >> 7;
            const int r = j & 127;
            const int p = r >> 3;
            const int i0 = (r & 7) * 16;
            const int row = tensor ? sqid[p] : sidx[p];
            const void* src = tensor ? q_emb : i_emb;
            float* dst = tensor ? qvT : ivT;
            float x[16];
            ld16<BF>(src, (long long)row * 128 + i0, x);
            #pragma unroll
            for (int k = 0; k < 16; ++k)
                dst[(i0 + k) * 16 + p] = x[k];   // banks vary with lane: ~2-way, free
        }
    }
    __syncthreads();

    const int g = t >> 6;    // 0=erase cols, 1=add cols, 2=w logits
    const int c = t & 63;

    if (g < 2) {
        const void* W = g ? add_W : erase_W;
        const float2 bb = ld2<BF>(g ? add_b : erase_b, c);
        float acc0[P1P], acc1[P1P];
        #pragma unroll
        for (int p = 0; p < P1P; ++p) { acc0[p] = bb.x; acc1[p] = bb.y; }

        #pragma unroll 4
        for (int i = 0; i < 128; ++i) {
            const float2 wv = ld2<BF>(W, i * 64 + c);     // cols 2c,2c+1 of row i
            const float4* ivr = (const float4*)&ivT[i * 16];
            const float4 x0 = ivr[0], x1 = ivr[1], x2 = ivr[2], x3 = ivr[3];
            const float xx[16] = {x0.x,x0.y,x0.z,x0.w, x1.x,x1.y,x1.z,x1.w,
                                  x2.x,x2.y,x2.z,x2.w, x3.x,x3.y,x3.z,x3.w};
            #pragma unroll
            for (int p = 0; p < P1P; ++p) {
                acc0[p] += xx[p] * wv.x;
                acc1[p] += xx[p] * wv.y;
            }
        }
        if (g == 0) {
            #pragma unroll
            for (int p = 0; p < P1P; ++p) {
                const float o0 = 1.f / (1.f + expf(-acc0[p]));
                const float o1 = 1.f / (1.f + expf(-acc1[p]));
                ((float2*)(e_buf + (size_t)(p0 + p) * V_))[c] = make_float2(o0, o1);
            }
        } else {
            #pragma unroll
            for (int p = 0; p < P1P; ++p)
                ((float2*)(a_buf + (size_t)(p0 + p) * V_))[c] =
                    make_float2(tanhf(acc0[p]), tanhf(acc1[p]));
        }
    } else {
        float acc[P1P];
        #pragma unroll
        for (int p = 0; p < P1P; ++p) acc[p] = 0.f;
        #pragma unroll 4
        for (int i = 0; i < 128; ++i) {
            const float kv = ld<BF>(key_memory, i * C_ + c);
            const float4* qvr = (const float4*)&qvT[i * 16];
            const float4 x0 = qvr[0], x1 = qvr[1], x2 = qvr[2], x3 = qvr[3];
            const float xx[16] = {x0.x,x0.y,x0.z,x0.w, x1.x,x1.y,x1.z,x1.w,
                                  x2.x,x2.y,x2.z,x2.w, x3.x,x3.y,x3.z,x3.w};
            #pragma unroll
            for (int p = 0; p < P1P; ++p) acc[p] += xx[p] * kv;
        }
        #pragma unroll
        for (int p = 0; p < P1P; ++p) {
            float m = acc[p];
            for (int off = 32; off > 0; off >>= 1)
                m = fmaxf(m, __shfl_xor(m, off, 64));
            const float ex = expf(acc[p] - m);
            float ssum = ex;
            for (int off = 32; off > 0; off >>= 1)
                ssum += __shfl_xor(ssum, off, 64);
            w_buf[(size_t)(p0 + p) * C_ + c] = ex / ssum;
        }
    }
}

__global__ __launch_bounds__(192) void dkvmn_phase1(
    const void* q_emb, const void* i_emb, const void* key_memory,
    const void* erase_W, const void* erase_b, const void* add_W, const void* add_b,
    const int* __restrict__ input,
    float* e_buf, float* a_buf, float* w_buf, const int* __restrict__ flag)
{
    __shared__ float ivT[128 * P1P];
    __shared__ float qvT[128 * P1P];
    __shared__ int sidx[P1P], sqid[P1P];
    if (*flag)
        phase1_body<true>(q_emb, i_emb, key_memory, erase_W, erase_b, add_W, add_b,
                          input, e_buf, a_buf, w_buf, ivT, qvT, sidx, sqid);
    else
        phase1_body<false>(q_emb, i_emb, key_memory, erase_W, erase_b, add_W, add_b,
                           input, e_buf, a_buf, w_buf, ivT, qvT, sidx, sqid);
}

// ================= Phase 2: register scan, 1 wave / (b, 4-v group) =================
template<bool BF>
__device__ __forceinline__ void phase2_body(
    const void* q_emb, const void* key_memory, const void* init_value_memory,
    const int* __restrict__ target_id,
    const float* __restrict__ e_buf, const float* __restrict__ a_buf,
    const float* __restrict__ w_buf, float* __restrict__ read_buf)
{
    const int bid = blockIdx.x;
    const int b = bid >> 5;       // 32 blocks per batch element
    const int vg = bid & 31;      // v = vg*4 + j
    const int c = threadIdx.x;    // 0..63

    float mem[4];
    #pragma unroll
    for (int j = 0; j < 4; ++j)
        mem[j] = ld<BF>(init_value_memory, (vg * 4 + j) * C_ + c);

    const float* eb = e_buf + (size_t)b * S_ * V_ + vg * 4;
    const float* ab = a_buf + (size_t)b * S_ * V_ + vg * 4;
    const float* wb = w_buf + (size_t)b * S_ * C_ + c;

    float4 eN = *(const float4*)eb;
    float4 aN = *(const float4*)ab;
    float  wN = *wb;
    for (int s = 0; s < S_; ++s) {
        const float4 eC = eN, aC = aN;
        const float wC = wN;
        if (s + 1 < S_) {
            eN = *(const float4*)(eb + (size_t)(s + 1) * V_);
            aN = *(const float4*)(ab + (size_t)(s + 1) * V_);
            wN = wb[(size_t)(s + 1) * C_];
        }
        // mem = mem*(1 - e*w) + a*w  ==  mem + w*(a - mem*e)
        mem[0] = fmaf(wC, fmaf(-mem[0], eC.x, aC.x), mem[0]);
        mem[1] = fmaf(wC, fmaf(-mem[1], eC.y, aC.y), mem[1]);
        mem[2] = fmaf(wC, fmaf(-mem[2], eC.z, aC.z), mem[2]);
        mem[3] = fmaf(wC, fmaf(-mem[3], eC.w, aC.w), mem[3]);
    }

    // wt = softmax_c(qv @ key_memory), computed redundantly per block
    const long long qrow = (long long)target_id[b] * K_;
    float logit = 0.f;
    #pragma unroll 8
    for (int i = 0; i < K_; ++i)
        logit += ld<BF>(q_emb, qrow + i) * ld<BF>(key_memory, i * C_ + c);
    float m = logit;
    for (int off = 32; off > 0; off >>= 1)
        m = fmaxf(m, __shfl_xor(m, off, 64));
    const float ex = expf(logit - m);
    float ssum = ex;
    for (int off = 32; off > 0; off >>= 1)
        ssum += __shfl_xor(ssum, off, 64);
    const float wt = ex / ssum;

    #pragma unroll
    for (int j = 0; j < 4; ++j) {
        float r = mem[j] * wt;
        for (int off = 32; off > 0; off >>= 1)
            r += __shfl_xor(r, off, 64);
        if (c == 0) read_buf[b * V_ + vg * 4 + j] = r;
    }
}

__global__ __launch_bounds__(64) void dkvmn_phase2(
    const void* q_emb, const void* key_memory, const void* init_value_memory,
    const int* __restrict__ target_id,
    const float* e_buf, const float* a_buf, const float* w_buf,
    float* read_buf, const int* __restrict__ flag)
{
    if (*flag)
        phase2_body<true>(q_emb, key_memory, init_value_memory, target_id,
                          e_buf, a_buf, w_buf, read_buf);
    else
        phase2_body<false>(q_emb, key_memory, init_value_memory, target_id,
                           e_buf, a_buf, w_buf, read_buf);
}

// ================= Phase 3: summ mat-vec + scalar out =================
template<bool BF>
__device__ __forceinline__ void phase3_body(
    const void* q_emb, const void* summ_W, const void* summ_b,
    const void* out_W, const void* out_b,
    const int* __restrict__ target_id, const float* __restrict__ read_buf,
    void* outp, float* summl)
{
    const int b = blockIdx.x;
    const int t = threadIdx.x;  // 0..127
    const long long qrow = (long long)target_id[b] * K_;

    float acc = ld<BF>(summ_b, t);
    #pragma unroll 4
    for (int i = 0; i < 128; ++i)
        acc += read_buf[b * V_ + i] * ld<BF>(summ_W, i * SUM_ + t);
    #pragma unroll 4
    for (int i = 0; i < 128; ++i)
        acc += ld<BF>(q_emb, qrow + i) * ld<BF>(summ_W, (128 + i) * SUM_ + t);
    summl[t] = tanhf(acc);
    __syncthreads();

    if (t < 64) {
        float pacc = summl[t] * ld<BF>(out_W, t) + summl[t + 64] * ld<BF>(out_W, t + 64);
        for (int off = 32; off > 0; off >>= 1)
            pacc += __shfl_xor(pacc, off, 64);
        if (t == 0) {
            const float res = pacc + ld<BF>(out_b, 0);
            if (BF) ((__hip_bfloat16*)outp)[b] = __float2bfloat16(res);
            else    ((float*)outp)[b] = res;
        }
    }
}

__global__ __launch_bounds__(128) void dkvmn_phase3(
    const void* q_emb, const void* summ_W, const void* summ_b,
    const void* out_W, const void* out_b,
    const int* __restrict__ target_id, const float* read_buf,
    void* outp, const int* __restrict__ flag)
{
    __shared__ float summl[SUM_];
    if (*flag)
        phase3_body<true>(q_emb, summ_W, summ_b, out_W, out_b, target_id,
                          read_buf, outp, summl);
    else
        phase3_body<false>(q_emb, summ_W, summ_b, out_W, out_b, target_id,
                           read_buf, outp, summl);
}

extern "C" void kernel_launch(void* const* d_in, const int* in_sizes, int n_in,
                              void* d_out, int out_size, void* d_ws, size_t ws_size,
                              hipStream_t stream) {
    const void* q_emb             = d_in[0];
    const void* i_emb             = d_in[1];
    const void* key_memory        = d_in[2];
    const void* init_value_memory = d_in[3];
    const void* erase_W           = d_in[4];
    const void* erase_b           = d_in[5];
    const void* add_W             = d_in[6];
    const void* add_b             = d_in[7];
    const void* summ_W            = d_in[8];
    const void* summ_b            = d_in[9];
    const void* out_W             = d_in[10];
    const void* out_b             = d_in[11];
    const int* input     = (const int*)d_in[12];
    const int* target_id = (const int*)d_in[13];

    // ws: [flag 64B][e B*S*V f32][a B*S*V f32][w B*S*C f32][read B*V f32]
    int* flag       = (int*)d_ws;
    float* e_buf    = (float*)((char*)d_ws + 64);
    float* a_buf    = e_buf + (size_t)B_ * S_ * V_;
    float* w_buf    = a_buf + (size_t)B_ * S_ * V_;
    float* read_buf = w_buf + (size_t)B_ * S_ * C_;

    dtype_probe<<<1, 64, 0, stream>>>(erase_b, flag);
    dkvmn_phase1<<<(B_ * S_) / P1P, 192, 0, stream>>>(
        q_emb, i_emb, key_memory, erase_W, erase_b, add_W, add_b,
        input, e_buf, a_buf, w_buf, flag);
    dkvmn_phase2<<<B_ * 32, 64, 0, stream>>>(
        q_emb, key_memory, init_value_memory, target_id,
        e_buf, a_buf, w_buf, read_buf, flag);
    dkvmn_phase3<<<B_, 128, 0, stream>>>(
        q_emb, summ_W, summ_b, out_W, out_b, target_id, read_buf, d_out, flag);
}